// Round 8
// baseline (117.167 us; speedup 1.0000x reference)
//
#include <hip/hip_runtime.h>

#define NROWS 131072
#define DDIM  64
#define KCTR  512
#define OUT_W 577                 /* 1 + 64 + 512 */
#define RPB   16                  /* rows per tile */
#define NTILES (NROWS / RPB)      /* 8192 */
#define SPAN_F32 (RPB * OUT_W)    /* 9232 floats = 36928 B */
#define SPAN_V4  (SPAN_F32 / 4)   /* 2308 = 9*256 + 4 */
#define GRID 1024                 /* 4 blocks/CU x 256 CU, persistent */
#define ROUNDS (NTILES / GRID)    /* 8, exact */
#define K_HALF_LN2 0.34657359027997264f   /* 0.5*ln(2) */

typedef __attribute__((ext_vector_type(8))) short bfrag8;
typedef __attribute__((ext_vector_type(4))) float f32x4;

__device__ __forceinline__ short f2bf(float f) {
    union { float f; unsigned u; } v; v.f = f;
    return (short)((v.u + 0x8000u) >> 16);   // round-to-nearest
}

// __syncthreads minus the vmcnt(0) drain: waits only LDS ops, leaves global
// stores/loads in flight across the barrier.
__device__ __forceinline__ void lds_barrier() {
    asm volatile("s_waitcnt lgkmcnt(0)" ::: "memory");
    __builtin_amdgcn_s_barrier();
    __builtin_amdgcn_sched_barrier(0);
}

__global__ __launch_bounds__(256, 4) void dicrbf_mfma(
    const float* __restrict__ data,
    const float* __restrict__ centers,
    float* __restrict__ out)
{
    __shared__ __align__(16) float s_span[SPAN_F32];   // 36928 B, single buffer
    __shared__ short s_dbf[RPB][DDIM];                 // packed bf16 tile, 2048 B, XOR-swizzled
    __shared__ float s_xsq[RPB];                       // 64 B
    // total 39040 B -> 4 blocks/CU

    const int t    = threadIdx.x;
    const int lane = t & 63;
    const int wid  = t >> 6;
    const int l15  = lane & 15;
    const int lhi  = lane >> 4;
    const int cbase = wid * 128;          // this wave's 128 centers

    // ---- Prologue A: center norms -> span-scratch (span[0..511]) ----
    for (int k = t; k < KCTR; k += 256) {
        const f32x4* c4 = reinterpret_cast<const f32x4*>(centers + (size_t)k * DDIM);
        float s = 0.f;
#pragma unroll
        for (int i = 0; i < DDIM / 4; ++i) {
            f32x4 u = c4[i];
            s += u[0]*u[0] + u[1]*u[1] + u[2]*u[2] + u[3]*u[3];
        }
        s_span[k] = s;
    }

    // ---- Prologue B: A-fragments = bf16(-2*center) -> registers ----
    // lane (l15,lhi): center row cbase+mf*16+l15, cols ks*32+lhi*8..+7
    bfrag8 afr[8][2];
#pragma unroll
    for (int mf = 0; mf < 8; ++mf) {
        const float* cp = centers + (size_t)(cbase + mf * 16 + l15) * DDIM + lhi * 8;
#pragma unroll
        for (int ks = 0; ks < 2; ++ks) {
            const f32x4 u0 = *reinterpret_cast<const f32x4*>(cp + ks * 32);
            const f32x4 u1 = *reinterpret_cast<const f32x4*>(cp + ks * 32 + 4);
            bfrag8 fr;
            fr[0] = f2bf(-2.f*u0[0]); fr[1] = f2bf(-2.f*u0[1]);
            fr[2] = f2bf(-2.f*u0[2]); fr[3] = f2bf(-2.f*u0[3]);
            fr[4] = f2bf(-2.f*u1[0]); fr[5] = f2bf(-2.f*u1[1]);
            fr[6] = f2bf(-2.f*u1[2]); fr[7] = f2bf(-2.f*u1[3]);
            afr[mf][ks] = fr;
        }
    }
    __syncthreads();   // norms visible

    // per-lane center norms (4 consecutive centers per mf) -> registers
    f32x4 cnr[8];
#pragma unroll
    for (int mf = 0; mf < 8; ++mf)
        cnr[mf] = *reinterpret_cast<const f32x4*>(&s_span[cbase + mf * 16 + lhi * 4]);
    __syncthreads();   // everyone has cnr; span free for reuse

    // ---- Persistent tile loop: 3 lds_barriers/round, no vmcnt drains ----
    const int r  = t >> 4;      // row within tile
    const int jj = t & 15;      // 4-float chunk within row
    // dbf XOR-swizzle (packed [16][64] shorts): 16B unit u at row r -> u^(r&7)
    const int dbf_waddr = r * 64 + (((jj >> 1) ^ (r & 7)) << 3) + ((jj & 1) << 2);

    size_t tile = blockIdx.x;
    f32x4 v = *reinterpret_cast<const f32x4*>(data + (tile * RPB + r) * DDIM + jj * 4);

    for (int round = 0; round < ROUNDS; ++round, tile += GRID) {
        // P1: xsq reduce + passthrough into span + swizzled bf16 tile; prefetch
        float s = v[0]*v[0] + v[1]*v[1] + v[2]*v[2] + v[3]*v[3];
        s += __shfl_xor(s, 1);
        s += __shfl_xor(s, 2);
        s += __shfl_xor(s, 4);
        s += __shfl_xor(s, 8);
        if (jj == 0) { s_xsq[r] = s; s_span[r * OUT_W] = 1.0f; }

        float* spv = &s_span[r * OUT_W + 1 + jj * 4];
        spv[0] = v[0]; spv[1] = v[1]; spv[2] = v[2]; spv[3] = v[3];

        short b4[4] = { f2bf(v[0]), f2bf(v[1]), f2bf(v[2]), f2bf(v[3]) };
        *reinterpret_cast<uint2*>(&s_dbf[0][0] + dbf_waddr) =
            *reinterpret_cast<const uint2*>(b4);

        if (round + 1 < ROUNDS)
            v = *reinterpret_cast<const f32x4*>(
                data + ((tile + GRID) * RPB + r) * DDIM + jj * 4);

        lds_barrier();   // (B1) dbf/xsq/passthrough visible

        // P2: B fragments from swizzled dbf; MFMA with C-init = xsq+cn;
        // epilogue straight into span
        const short* dbase = &s_dbf[0][0] + l15 * 64;
        const bfrag8 b0 = *reinterpret_cast<const bfrag8*>(
            dbase + (((0 * 4 + lhi) ^ (l15 & 7)) << 3));
        const bfrag8 b1 = *reinterpret_cast<const bfrag8*>(
            dbase + (((1 * 4 + lhi) ^ (l15 & 7)) << 3));
        const float xsq = s_xsq[l15];

#pragma unroll
        for (int mf = 0; mf < 8; ++mf) {
            f32x4 acc;
#pragma unroll
            for (int k = 0; k < 4; ++k) acc[k] = xsq + cnr[mf][k];
            acc = __builtin_amdgcn_mfma_f32_16x16x32_bf16(afr[mf][0], b0, acc, 0, 0, 0);
            acc = __builtin_amdgcn_mfma_f32_16x16x32_bf16(afr[mf][1], b1, acc, 0, 0, 0);

            float* sp = &s_span[l15 * OUT_W + 1 + DDIM + cbase + mf * 16 + lhi * 4];
#pragma unroll
            for (int k = 0; k < 4; ++k) {
                const float d2 = fmaxf(acc[k], 1e-30f);   // clamps negatives; ~0 stays ~0
                sp[k] = (K_HALF_LN2 * d2) * __log2f(d2);
            }
        }

        lds_barrier();   // (B2) span complete

        // P3: stream span out — aligned, fully coalesced
        const f32x4* sp4 = reinterpret_cast<const f32x4*>(s_span);
        f32x4* o4 = reinterpret_cast<f32x4*>(out) + tile * (size_t)SPAN_V4;
#pragma unroll
        for (int i = 0; i < 9; ++i)
            o4[t + i * 256] = sp4[t + i * 256];
        if (t < 4) o4[2304 + t] = sp4[2304 + t];

        lds_barrier();   // (B3) span reads retired; safe to overwrite next round
    }
}

extern "C" void kernel_launch(void* const* d_in, const int* in_sizes, int n_in,
                              void* d_out, int out_size, void* d_ws, size_t ws_size,
                              hipStream_t stream) {
    const float* data    = (const float*)d_in[0];
    const float* centers = (const float*)d_in[1];
    float* out = (float*)d_out;

    hipLaunchKernelGGL(dicrbf_mfma, dim3(GRID), dim3(256), 0, stream,
                       data, centers, out);
}